// Round 2
// baseline (142.942 us; speedup 1.0000x reference)
//
#include <hip/hip_runtime.h>
#include <math.h>

#define S 4096
#define B 16
#define R 8             // attention rows per wave

// ---------------------------------------------------------------------------
// Fused QKV skinny GEMM, latency-optimized: no LDS, no barriers.
// Grid: 768 blocks = 3 mats x 128 o-groups(32 rows) x 2 batch-halves.
// Each wave owns 8 W-rows x 8 batches (acc[8][8]); per iteration it issues
// 8 W float4 loads (prefetched one iteration ahead) + 8 x float4 loads,
// keeping ~16KB in flight per wave. W read once from HBM per b-half pair
// (paired blocks co-resident -> 2nd read hits L3); x is L1/L2-resident.
// ---------------------------------------------------------------------------
__global__ __launch_bounds__(256, 3) void qkv_kernel(
    const float* __restrict__ x,
    const float* __restrict__ Wq, const float* __restrict__ bq,
    const float* __restrict__ Wk, const float* __restrict__ bk,
    const float* __restrict__ Wv, const float* __restrict__ bv,
    float* __restrict__ q, float* __restrict__ k, float* __restrict__ v)
{
    const int tid  = threadIdx.x;
    const int lane = tid & 63;
    const int wave = tid >> 6;
    const int bx   = blockIdx.x;        // 0..767
    const int mat  = bx >> 8;           // 0:q 1:k 2:v
    const int rem  = bx & 255;
    const int og   = rem >> 1;          // 0..127 (32-row group)
    const int bh   = rem & 1;           // batch half

    const float* W    = (mat == 0) ? Wq : (mat == 1) ? Wk : Wv;
    const float* bias = (mat == 0) ? bq : (mat == 1) ? bk : bv;
    float*       out  = (mat == 0) ? q  : (mat == 1) ? k  : v;
    const int o0 = og * 32 + wave * 8;

    const float* Wr[8];
    #pragma unroll
    for (int r = 0; r < 8; ++r) Wr[r] = W + (size_t)(o0 + r) * S;
    const float* xb = x + (size_t)(bh * 8) * S;

    float acc[8][8];
    #pragma unroll
    for (int r = 0; r < 8; ++r)
        #pragma unroll
        for (int bi = 0; bi < 8; ++bi) acc[r][bi] = 0.f;

    float4 wc[8];
    #pragma unroll
    for (int r = 0; r < 8; ++r) wc[r] = *(const float4*)&Wr[r][lane * 4];

    for (int it = 0; it < 16; ++it) {
        float4 wn[8];
        if (it < 15) {
            const int sg = (it + 1) * 256 + lane * 4;
            #pragma unroll
            for (int r = 0; r < 8; ++r) wn[r] = *(const float4*)&Wr[r][sg];
        }
        const int sl = it * 256 + lane * 4;
        #pragma unroll
        for (int bi = 0; bi < 8; ++bi) {
            float4 xv = *(const float4*)&xb[(size_t)bi * S + sl];
            #pragma unroll
            for (int r = 0; r < 8; ++r) {
                acc[r][bi] = fmaf(wc[r].x, xv.x, acc[r][bi]);
                acc[r][bi] = fmaf(wc[r].y, xv.y, acc[r][bi]);
                acc[r][bi] = fmaf(wc[r].z, xv.z, acc[r][bi]);
                acc[r][bi] = fmaf(wc[r].w, xv.w, acc[r][bi]);
            }
        }
        #pragma unroll
        for (int r = 0; r < 8; ++r) wc[r] = wn[r];
    }

    // cross-lane reduction; lane (r*8+bi) writes output (bh*8+bi, o0+r)
    #pragma unroll
    for (int r = 0; r < 8; ++r) {
        #pragma unroll
        for (int bi = 0; bi < 8; ++bi) {
            float s = acc[r][bi];
            #pragma unroll
            for (int off = 32; off; off >>= 1) s += __shfl_xor(s, off, 64);
            if (lane == r * 8 + bi)
                out[(size_t)(bh * 8 + bi) * S + o0 + r] = s + bias[o0 + r];
        }
    }
}

// ---------------------------------------------------------------------------
// Inclusive prefix max/min of k per batch row. 16 blocks x 256 threads.
// ---------------------------------------------------------------------------
__global__ __launch_bounds__(256) void scan_kernel(
    const float* __restrict__ k,
    float* __restrict__ rmax, float* __restrict__ rmin)
{
    __shared__ float smax[256], smin[256];
    const int b = blockIdx.x, t = threadIdx.x;
    const float* kb = k + b * S;

    float seg[16];
    float lmax = -INFINITY, lmin = INFINITY;
    #pragma unroll
    for (int e = 0; e < 16; ++e) {
        seg[e] = kb[t * 16 + e];
        lmax = fmaxf(lmax, seg[e]);
        lmin = fminf(lmin, seg[e]);
    }
    smax[t] = lmax; smin[t] = lmin;
    __syncthreads();
    for (int off = 1; off < 256; off <<= 1) {
        float vx = (t >= off) ? smax[t - off] : -INFINITY;
        float vn = (t >= off) ? smin[t - off] :  INFINITY;
        __syncthreads();
        smax[t] = fmaxf(smax[t], vx);
        smin[t] = fminf(smin[t], vn);
        __syncthreads();
    }
    float runmax = (t > 0) ? smax[t - 1] : -INFINITY;
    float runmin = (t > 0) ? smin[t - 1] :  INFINITY;
    #pragma unroll
    for (int e = 0; e < 16; ++e) {
        runmax = fmaxf(runmax, seg[e]);
        runmin = fminf(runmin, seg[e]);
        rmax[b * S + t * 16 + e] = runmax;
        rmin[b * S + t * 16 + e] = runmin;
    }
}

// ---------------------------------------------------------------------------
// d=1 causal attention, single pass (row max known from prefix scan).
// Wave handles R=8 consecutive rows of one batch, sharing k/v loads.
// ---------------------------------------------------------------------------
__global__ __launch_bounds__(256) void attn_kernel(
    const float* __restrict__ q, const float* __restrict__ k,
    const float* __restrict__ v,
    const float* __restrict__ rmax, const float* __restrict__ rmin,
    float* __restrict__ out)
{
    const int tid = threadIdx.x, lane = tid & 63, wave = tid >> 6;
    const int task = blockIdx.x * 4 + wave;     // 0..8191
    const int b    = task & 15;
    const int rbi  = task >> 4;                 // 0..511
    const int i0   = (511 - rbi) * R;           // descending: big rows first
    const float* kb = k + b * S;
    const float* vb = v + b * S;
    const float LOG2E = 1.4426950408889634f;

    float a[R], cc[R], den[R], num[R];
    #pragma unroll
    for (int r = 0; r < R; ++r) {
        float qi = q[b * S + i0 + r];
        float m  = (qi >= 0.f) ? qi * rmax[b * S + i0 + r]
                               : qi * rmin[b * S + i0 + r];
        a[r]  = qi * LOG2E;
        cc[r] = -m * LOG2E;
        den[r] = 0.f; num[r] = 0.f;
    }

    const int nfull = (i0 + 1) >> 8;            // full 256-wide chunks
    for (int it = 0; it < nfull; ++it) {
        const int j = it * 256 + lane * 4;
        float4 k4 = *(const float4*)&kb[j];
        float4 v4 = *(const float4*)&vb[j];
        #pragma unroll
        for (int jj = 0; jj < 4; ++jj) {
            float kx = (&k4.x)[jj], vx = (&v4.x)[jj];
            #pragma unroll
            for (int r = 0; r < R; ++r) {
                float e = exp2f(fmaf(a[r], kx, cc[r]));
                den[r] += e;
                num[r] = fmaf(e, vx, num[r]);
            }
        }
    }
    // masked tail
    const int imax = i0 + R - 1;
    for (int j = nfull * 256 + lane; j <= imax; j += 64) {
        float kx = kb[j], vx = vb[j];
        #pragma unroll
        for (int r = 0; r < R; ++r) {
            float e = (j <= i0 + r) ? exp2f(fmaf(a[r], kx, cc[r])) : 0.f;
            den[r] += e;
            num[r] = fmaf(e, vx, num[r]);
        }
    }

    #pragma unroll
    for (int r = 0; r < R; ++r) {
        float d = den[r], n = num[r];
        #pragma unroll
        for (int off = 32; off; off >>= 1) {
            d += __shfl_xor(d, off, 64);
            n += __shfl_xor(n, off, 64);
        }
        if (lane == r) out[b * S + i0 + r] = n / d;
    }
}

extern "C" void kernel_launch(void* const* d_in, const int* in_sizes, int n_in,
                              void* d_out, int out_size, void* d_ws, size_t ws_size,
                              hipStream_t stream) {
    const float* x  = (const float*)d_in[0];
    const float* Wq = (const float*)d_in[1];
    const float* bq = (const float*)d_in[2];
    const float* Wk = (const float*)d_in[3];
    const float* bk = (const float*)d_in[4];
    const float* Wv = (const float*)d_in[5];
    const float* bv = (const float*)d_in[6];
    float* out = (float*)d_out;

    float* ws   = (float*)d_ws;
    float* q    = ws;                // 16*4096
    float* k    = ws + 65536;
    float* v    = ws + 131072;
    float* rmax = ws + 196608;
    float* rmin = ws + 262144;       // total 1.25 MB scratch

    qkv_kernel<<<768, 256, 0, stream>>>(x, Wq, bq, Wk, bk, Wv, bv, q, k, v);
    scan_kernel<<<16, 256, 0, stream>>>(k, rmax, rmin);
    attn_kernel<<<2048, 256, 0, stream>>>(q, k, v, rmax, rmin, out);
}

// Round 4
// 104.017 us; speedup vs baseline: 1.3742x; 1.3742x over previous
//
#include <hip/hip_runtime.h>
#include <math.h>

#define S 4096
#define B 16
#define SC 256          // s-chunk staged in LDS (16 x 256 fp32 = 16 KB)
#define R 8             // attention rows per wave

// ---------------------------------------------------------------------------
// Fused QKV skinny GEMM. Grid: 1536 blocks = 3 mats x 512 row-groups(8 rows).
// Block = 4 waves; wave owns 4 W-rows x 8 batches (acc[4][8] = 32 VGPR —
// deliberately small: rounds 1-2 spilled ~1GB to scratch at acc=64+).
// x is staged per-chunk in LDS; each W element read once from HBM.
// `#pragma unroll 1` on the chunk loop prevents unroll-driven register
// explosion (the round-1/2 spill cause).
// ---------------------------------------------------------------------------
__global__ __launch_bounds__(256) void qkv_kernel(
    const float* __restrict__ x,
    const float* __restrict__ Wq, const float* __restrict__ bq,
    const float* __restrict__ Wk, const float* __restrict__ bk,
    const float* __restrict__ Wv, const float* __restrict__ bv,
    float* __restrict__ q, float* __restrict__ k, float* __restrict__ v)
{
    __shared__ float xs[B][SC];
    const int tid  = threadIdx.x;
    const int lane = tid & 63;
    const int wave = tid >> 6;
    const int bx   = blockIdx.x;        // 0..1535
    const int mat  = bx >> 9;           // 0:q 1:k 2:v
    const int og   = bx & 511;          // 8-row group

    const float* W    = (mat == 0) ? Wq : (mat == 1) ? Wk : Wv;
    const float* bias = (mat == 0) ? bq : (mat == 1) ? bk : bv;
    float*       out  = (mat == 0) ? q  : (mat == 1) ? k  : v;
    const int o0  = og * 8 + (wave >> 1) * 4;   // this wave's 4 W-rows
    const int bb0 = (wave & 1) * 8;             // this wave's 8 batches
    const float* Wp = W + (size_t)o0 * S;

    float acc[4][8];
    #pragma unroll
    for (int r = 0; r < 4; ++r)
        #pragma unroll
        for (int bi = 0; bi < 8; ++bi) acc[r][bi] = 0.f;

    #pragma unroll 1
    for (int c = 0; c < S / SC; ++c) {
        __syncthreads();                // previous chunk fully consumed
        #pragma unroll
        for (int r = 0; r < (B * SC / 4) / 256; ++r) {
            int f4 = tid + r * 256;
            int b  = f4 >> 6;           // SC/4 = 64 float4 per row
            int s4 = f4 & 63;
            *(float4*)&xs[b][s4 * 4] =
                *(const float4*)&x[(size_t)b * S + c * SC + s4 * 4];
        }
        __syncthreads();
        const int sg = c * SC + lane * 4;
        float4 w0 = *(const float4*)&Wp[0 * S + sg];
        float4 w1 = *(const float4*)&Wp[1 * S + sg];
        float4 w2 = *(const float4*)&Wp[2 * S + sg];
        float4 w3 = *(const float4*)&Wp[3 * S + sg];
        #pragma unroll
        for (int bi = 0; bi < 8; ++bi) {
            float4 xv = *(const float4*)&xs[bb0 + bi][lane * 4];
            acc[0][bi] = fmaf(w0.x, xv.x, acc[0][bi]);
            acc[0][bi] = fmaf(w0.y, xv.y, acc[0][bi]);
            acc[0][bi] = fmaf(w0.z, xv.z, acc[0][bi]);
            acc[0][bi] = fmaf(w0.w, xv.w, acc[0][bi]);
            acc[1][bi] = fmaf(w1.x, xv.x, acc[1][bi]);
            acc[1][bi] = fmaf(w1.y, xv.y, acc[1][bi]);
            acc[1][bi] = fmaf(w1.z, xv.z, acc[1][bi]);
            acc[1][bi] = fmaf(w1.w, xv.w, acc[1][bi]);
            acc[2][bi] = fmaf(w2.x, xv.x, acc[2][bi]);
            acc[2][bi] = fmaf(w2.y, xv.y, acc[2][bi]);
            acc[2][bi] = fmaf(w2.z, xv.z, acc[2][bi]);
            acc[2][bi] = fmaf(w2.w, xv.w, acc[2][bi]);
            acc[3][bi] = fmaf(w3.x, xv.x, acc[3][bi]);
            acc[3][bi] = fmaf(w3.y, xv.y, acc[3][bi]);
            acc[3][bi] = fmaf(w3.z, xv.z, acc[3][bi]);
            acc[3][bi] = fmaf(w3.w, xv.w, acc[3][bi]);
        }
    }

    // cross-lane reduction; lane (r*8+bi) writes output (bb0+bi, o0+r)
    #pragma unroll
    for (int r = 0; r < 4; ++r) {
        #pragma unroll
        for (int bi = 0; bi < 8; ++bi) {
            float s = acc[r][bi];
            #pragma unroll
            for (int off = 32; off; off >>= 1) s += __shfl_xor(s, off, 64);
            if (lane == r * 8 + bi)
                out[(size_t)(bb0 + bi) * S + o0 + r] = s + bias[o0 + r];
        }
    }
}

// ---------------------------------------------------------------------------
// Inclusive prefix max/min of k per batch row. 16 blocks x 256 threads.
// ---------------------------------------------------------------------------
__global__ __launch_bounds__(256) void scan_kernel(
    const float* __restrict__ k,
    float* __restrict__ rmax, float* __restrict__ rmin)
{
    __shared__ float smax[256], smin[256];
    const int b = blockIdx.x, t = threadIdx.x;
    const float* kb = k + b * S;

    float seg[16];
    float lmax = -INFINITY, lmin = INFINITY;
    #pragma unroll
    for (int e = 0; e < 16; ++e) {
        seg[e] = kb[t * 16 + e];
        lmax = fmaxf(lmax, seg[e]);
        lmin = fminf(lmin, seg[e]);
    }
    smax[t] = lmax; smin[t] = lmin;
    __syncthreads();
    for (int off = 1; off < 256; off <<= 1) {
        float vx = (t >= off) ? smax[t - off] : -INFINITY;
        float vn = (t >= off) ? smin[t - off] :  INFINITY;
        __syncthreads();
        smax[t] = fmaxf(smax[t], vx);
        smin[t] = fminf(smin[t], vn);
        __syncthreads();
    }
    float runmax = (t > 0) ? smax[t - 1] : -INFINITY;
    float runmin = (t > 0) ? smin[t - 1] :  INFINITY;
    #pragma unroll
    for (int e = 0; e < 16; ++e) {
        runmax = fmaxf(runmax, seg[e]);
        runmin = fminf(runmin, seg[e]);
        rmax[b * S + t * 16 + e] = runmax;
        rmin[b * S + t * 16 + e] = runmin;
    }
}

// ---------------------------------------------------------------------------
// d=1 causal attention, single pass (row max known from prefix scan).
// Wave handles R=8 consecutive rows of one batch, sharing k/v loads.
// ---------------------------------------------------------------------------
__global__ __launch_bounds__(256) void attn_kernel(
    const float* __restrict__ q, const float* __restrict__ k,
    const float* __restrict__ v,
    const float* __restrict__ rmax, const float* __restrict__ rmin,
    float* __restrict__ out)
{
    const int tid = threadIdx.x, lane = tid & 63, wave = tid >> 6;
    const int task = blockIdx.x * 4 + wave;     // 0..8191
    const int b    = task & 15;
    const int rbi  = task >> 4;                 // 0..511
    const int i0   = (511 - rbi) * R;           // descending: big rows first
    const float* kb = k + b * S;
    const float* vb = v + b * S;
    const float LOG2E = 1.4426950408889634f;

    float a[R], cc[R], den[R], num[R];
    #pragma unroll
    for (int r = 0; r < R; ++r) {
        float qi = q[b * S + i0 + r];
        float m  = (qi >= 0.f) ? qi * rmax[b * S + i0 + r]
                               : qi * rmin[b * S + i0 + r];
        a[r]  = qi * LOG2E;
        cc[r] = -m * LOG2E;
        den[r] = 0.f; num[r] = 0.f;
    }

    const int nfull = (i0 + 1) >> 8;            // full 256-wide chunks
    #pragma unroll 1
    for (int it = 0; it < nfull; ++it) {
        const int j = it * 256 + lane * 4;
        float4 k4 = *(const float4*)&kb[j];
        float4 v4 = *(const float4*)&vb[j];
        #pragma unroll
        for (int jj = 0; jj < 4; ++jj) {
            float kx = (&k4.x)[jj], vx = (&v4.x)[jj];
            #pragma unroll
            for (int r = 0; r < R; ++r) {
                float e = exp2f(fmaf(a[r], kx, cc[r]));
                den[r] += e;
                num[r] = fmaf(e, vx, num[r]);
            }
        }
    }
    // masked tail
    const int imax = i0 + R - 1;
    for (int j = nfull * 256 + lane; j <= imax; j += 64) {
        float kx = kb[j], vx = vb[j];
        #pragma unroll
        for (int r = 0; r < R; ++r) {
            float e = (j <= i0 + r) ? exp2f(fmaf(a[r], kx, cc[r])) : 0.f;
            den[r] += e;
            num[r] = fmaf(e, vx, num[r]);
        }
    }

    #pragma unroll
    for (int r = 0; r < R; ++r) {
        float d = den[r], n = num[r];
        #pragma unroll
        for (int off = 32; off; off >>= 1) {
            d += __shfl_xor(d, off, 64);
            n += __shfl_xor(n, off, 64);
        }
        if (lane == r) out[b * S + i0 + r] = n / d;
    }
}

extern "C" void kernel_launch(void* const* d_in, const int* in_sizes, int n_in,
                              void* d_out, int out_size, void* d_ws, size_t ws_size,
                              hipStream_t stream) {
    const float* x  = (const float*)d_in[0];
    const float* Wq = (const float*)d_in[1];
    const float* bq = (const float*)d_in[2];
    const float* Wk = (const float*)d_in[3];
    const float* bk = (const float*)d_in[4];
    const float* Wv = (const float*)d_in[5];
    const float* bv = (const float*)d_in[6];
    float* out = (float*)d_out;

    float* ws   = (float*)d_ws;
    float* q    = ws;                // 16*4096
    float* k    = ws + 65536;
    float* v    = ws + 131072;
    float* rmax = ws + 196608;
    float* rmin = ws + 262144;       // total 1.25 MB scratch

    qkv_kernel<<<1536, 256, 0, stream>>>(x, Wq, bq, Wk, bk, Wv, bv, q, k, v);
    scan_kernel<<<16, 256, 0, stream>>>(k, rmax, rmin);
    attn_kernel<<<2048, 256, 0, stream>>>(q, k, v, rmax, rmin, out);
}